// Round 8
// baseline (4792.246 us; speedup 1.0000x reference)
//
#include <hip/hip_runtime.h>
#include <hip/hip_cooperative_groups.h>
#include <math.h>

namespace cg = cooperative_groups;

#define F_IN 512
#define HD 64
#define CD 16
#define K_HOPS 10

#define BKT_SHIFT 7
#define BKT_NODES 128
#define NBKT_MAX 1024
#define EPB 8192

#define HOP_BLOCKS 2048

typedef unsigned int uint32;
typedef __attribute__((ext_vector_type(8))) short short8v;
typedef __attribute__((ext_vector_type(4))) float float4v;

static __device__ __forceinline__ float bf2f(unsigned short h) {
    return __uint_as_float(((uint32)h) << 16);
}
static __device__ __forceinline__ unsigned short f2bf(float x) {
    uint32 u = __float_as_uint(x);
    u = (u + 0x7FFFu + ((u >> 16) & 1u)) >> 16;   // RNE
    return (unsigned short)u;
}

// ---------------- CSR build: two-level bucket sort ----------------

__global__ void zero_kernel(int* __restrict__ p, int n) {
    int i = blockIdx.x * blockDim.x + threadIdx.x;
    if (i < n) p[i] = 0;
}

__global__ __launch_bounds__(256) void bucket_hist_kernel(
    const int* __restrict__ cols, int* __restrict__ bcnt, int e, int nb) {
    __shared__ int c[NBKT_MAX];
    int t = threadIdx.x;
    for (int i = t; i < nb; i += 256) c[i] = 0;
    __syncthreads();
    int base = blockIdx.x * EPB;
    int end = min(base + EPB, e);
    for (int i = base + t; i < end; i += 256)
        atomicAdd(&c[cols[i] >> BKT_SHIFT], 1);
    __syncthreads();
    for (int i = t; i < nb; i += 256)
        if (c[i]) atomicAdd(&bcnt[i], c[i]);
}

__global__ __launch_bounds__(256) void bucket_scan_kernel(
    const int* __restrict__ bcnt, int* __restrict__ bstart,
    int* __restrict__ bcur, int nb) {
    __shared__ int s[256];
    int t = threadIdx.x;
    int v[4]; int sum = 0;
#pragma unroll
    for (int i = 0; i < 4; ++i) {
        int idx = t * 4 + i;
        v[i] = (idx < nb) ? bcnt[idx] : 0;
        sum += v[i];
    }
    s[t] = sum; __syncthreads();
    for (int off = 1; off < 256; off <<= 1) {
        int x = (t >= off) ? s[t - off] : 0;
        __syncthreads();
        s[t] += x;
        __syncthreads();
    }
    int excl = s[t] - sum;
#pragma unroll
    for (int i = 0; i < 4; ++i) {
        int idx = t * 4 + i;
        if (idx < nb) { bstart[idx] = excl; bcur[idx] = excl; }
        excl += v[i];
    }
    if (t == 255) bstart[nb] = excl;
}

__global__ __launch_bounds__(256) void scatter_bin_kernel(
    const int* __restrict__ rows, const int* __restrict__ cols,
    int* __restrict__ bcur, uint32* __restrict__ stage, int e, int nb) {
    __shared__ int c[NBKT_MAX];
    int t = threadIdx.x;
    for (int i = t; i < nb; i += 256) c[i] = 0;
    __syncthreads();
    int base = blockIdx.x * EPB;
    int end = min(base + EPB, e);
    for (int i = base + t; i < end; i += 256)
        atomicAdd(&c[cols[i] >> BKT_SHIFT], 1);
    __syncthreads();
    for (int i = t; i < nb; i += 256) {
        int cc = c[i];
        if (cc) c[i] = atomicAdd(&bcur[i], cc);
    }
    __syncthreads();
    for (int i = base + t; i < end; i += 256) {
        int col = cols[i];
        int b = col >> BKT_SHIFT;
        int pos = atomicAdd(&c[b], 1);
        stage[pos] = ((uint32)rows[i] << BKT_SHIFT) | (uint32)(col & (BKT_NODES - 1));
    }
}

__global__ __launch_bounds__(256) void bucket_sort_kernel(
    const uint32* __restrict__ stage, const int* __restrict__ bstart,
    int* __restrict__ rowstart, float* __restrict__ dis,
    int* __restrict__ csr, int n, int e) {
    __shared__ int cnt[BKT_NODES];
    __shared__ int excl[BKT_NODES];
    __shared__ int lcur[BKT_NODES];
    int b = blockIdx.x, t = threadIdx.x;
    int s0 = bstart[b], s1 = bstart[b + 1];
    int nnode = min(BKT_NODES, n - b * BKT_NODES);
    if (t < BKT_NODES) cnt[t] = 0;
    __syncthreads();
    for (int i = s0 + t; i < s1; i += 256)
        atomicAdd(&cnt[stage[i] & (BKT_NODES - 1)], 1);
    __syncthreads();
    if (t < BKT_NODES) excl[t] = cnt[t];
    __syncthreads();
    for (int off = 1; off < BKT_NODES; off <<= 1) {
        int x = 0;
        if (t < BKT_NODES && t >= off) x = excl[t - off];
        __syncthreads();
        if (t < BKT_NODES) excl[t] += x;
        __syncthreads();
    }
    if (t < BKT_NODES) {
        int rs = s0 + excl[t] - cnt[t];
        lcur[t] = rs;
        if (t < nnode) {
            rowstart[b * BKT_NODES + t] = rs;
            dis[b * BKT_NODES + t] = rsqrtf((float)(cnt[t] + 1));
        }
    }
    if (b == 0 && t == 0) rowstart[n] = e;
    __syncthreads();
    for (int i = s0 + t; i < s1; i += 256) {
        uint32 v = stage[i];
        int pos = atomicAdd(&lcur[v & (BKT_NODES - 1)], 1);
        csr[pos] = (int)(v >> BKT_SHIFT);
    }
}

// ---------------- weight transpose + bf16 convert (one-time) -------------

__global__ void convw_kernel(const float* __restrict__ W1,
                             const float* __restrict__ W2,
                             unsigned short* __restrict__ w1t,
                             unsigned short* __restrict__ w2t) {
    int i = blockIdx.x * blockDim.x + threadIdx.x;
    if (i < HD * F_IN) {
        int h = i >> 9, k = i & 511;
        w1t[i] = f2bf(W1[k * HD + h]);
    } else {
        int j = i - HD * F_IN;
        if (j < CD * HD) {
            int c = j >> 6, k = j & 63;
            w2t[j] = f2bf(W2[k * CD + c]);
        }
    }
}

// ---------------- MFMA MLP + riemann + init ------------------------------

#define LSTR 72

__global__ __launch_bounds__(256) void mlp_kernel(
    const float* __restrict__ x, const unsigned short* __restrict__ w1t,
    const float* __restrict__ b1, const unsigned short* __restrict__ w2t,
    const float* __restrict__ b2, const float* __restrict__ dis,
    const float* __restrict__ temp, const float* __restrict__ wfn,
    unsigned short* __restrict__ g0, float* __restrict__ hidden, int n) {
    __shared__ __align__(16) unsigned short xb[64 * LSTR];
    __shared__ __align__(16) unsigned short w1b[64 * LSTR];
    __shared__ __align__(16) unsigned short w2b[16 * LSTR];

    const int t = threadIdx.x;
    const int row0 = blockIdx.x * 64;
    const int wave = t >> 6, lane = t & 63;
    const int l15 = lane & 15, lq = lane >> 4;
    const int lrow = (wave << 4) + l15;

    if (t < 128) {
        int cr = t >> 3, part = t & 7;
        *(short8v*)&w2b[cr * LSTR + part * 8] =
            *(const short8v*)&w2t[cr * HD + part * 8];
    }

    float4v acc[4];
#pragma unroll
    for (int i = 0; i < 4; ++i) acc[i] = (float4v)0.0f;

    const int srow = t >> 2, spart = t & 3;
    for (int c = 0; c < F_IN / 64; ++c) {
        __syncthreads();
        {
            int gr = row0 + srow; if (gr >= n) gr = n - 1;
            const float* xp = x + (long)gr * F_IN + c * 64 + spart * 16;
            float4 v0 = *(const float4*)(xp + 0);
            float4 v1 = *(const float4*)(xp + 4);
            float4 v2 = *(const float4*)(xp + 8);
            float4 v3 = *(const float4*)(xp + 12);
            short8v o0, o1;
            o0[0] = (short)f2bf(v0.x); o0[1] = (short)f2bf(v0.y);
            o0[2] = (short)f2bf(v0.z); o0[3] = (short)f2bf(v0.w);
            o0[4] = (short)f2bf(v1.x); o0[5] = (short)f2bf(v1.y);
            o0[6] = (short)f2bf(v1.z); o0[7] = (short)f2bf(v1.w);
            o1[0] = (short)f2bf(v2.x); o1[1] = (short)f2bf(v2.y);
            o1[2] = (short)f2bf(v2.z); o1[3] = (short)f2bf(v2.w);
            o1[4] = (short)f2bf(v3.x); o1[5] = (short)f2bf(v3.y);
            o1[6] = (short)f2bf(v3.z); o1[7] = (short)f2bf(v3.w);
            *(short8v*)&xb[srow * LSTR + spart * 16] = o0;
            *(short8v*)&xb[srow * LSTR + spart * 16 + 8] = o1;
            const unsigned short* wp = w1t + srow * F_IN + c * 64 + spart * 16;
            *(short8v*)&w1b[srow * LSTR + spart * 16] = *(const short8v*)(wp);
            *(short8v*)&w1b[srow * LSTR + spart * 16 + 8] = *(const short8v*)(wp + 8);
        }
        __syncthreads();
#pragma unroll
        for (int st = 0; st < 2; ++st) {
            int kb = st * 32 + lq * 8;
            short8v av = *(const short8v*)&xb[lrow * LSTR + kb];
#pragma unroll
            for (int hf = 0; hf < 4; ++hf) {
                short8v bv = *(const short8v*)&w1b[(hf * 16 + l15) * LSTR + kb];
                acc[hf] = __builtin_amdgcn_mfma_f32_16x16x32_bf16(av, bv, acc[hf], 0, 0, 0);
            }
        }
    }

    __syncthreads();
    {
        int drow = (wave << 4) + (lq << 2);
#pragma unroll
        for (int hf = 0; hf < 4; ++hf) {
            int h = hf * 16 + l15;
            float bv = b1[h];
#pragma unroll
            for (int i = 0; i < 4; ++i) {
                float v = acc[hf][i] + bv;
                v = v > 0.0f ? v : 0.0f;
                xb[(drow + i) * LSTR + h] = f2bf(v);
            }
        }
    }
    __syncthreads();

    float4v acc2 = (float4v)0.0f;
#pragma unroll
    for (int st = 0; st < 2; ++st) {
        int kb = st * 32 + lq * 8;
        short8v av = *(const short8v*)&xb[lrow * LSTR + kb];
        short8v bv = *(const short8v*)&w2b[l15 * LSTR + kb];
        acc2 = __builtin_amdgcn_mfma_f32_16x16x32_bf16(av, bv, acc2, 0, 0, 0);
    }

    {
        const int cc = l15;
        const int drow = (wave << 4) + (lq << 2);
        float b2c = b2[cc];
        float wabs = fabsf(wfn[cc]);
        float o[4], p[4];
#pragma unroll
        for (int i = 0; i < 4; ++i) {
            o[i] = acc2[i] + b2c;
            p[i] = o[i] * o[i] * wabs;
        }
#pragma unroll
        for (int off = 1; off < 16; off <<= 1) {
#pragma unroll
            for (int i = 0; i < 4; ++i) p[i] += __shfl_xor(p[i], off);
        }
        float t0 = temp[0];
#pragma unroll
        for (int i = 0; i < 4; ++i) {
            int grow = row0 + drow + i;
            if (grow < n) {
                float inv = 1.0f / (sqrtf(p[i] + 0.01f) + 0.01f);
                float hn = o[i] * inv;
                float d = dis[grow];
                hidden[(long)grow * CD + cc] = t0 * hn;
                g0[(long)grow * CD + cc] = f2bf(d * hn);
            }
        }
    }
}

// ---------------- hop body (shared by coop + fallback) -------------------
// wave/node, 16 edge-slots x 4 feat-lanes, depth-1 csr prefetch pipeline.

static __device__ __forceinline__ void hop_sweeps(
    const unsigned short* __restrict__ g, unsigned short* __restrict__ gn,
    float* __restrict__ hidden, const float* __restrict__ dis,
    const int* __restrict__ rowstart, const int* __restrict__ csr,
    float tk, int writeg, int n, int etot,
    int wv, int NW, int slot, int fl,
    float wx, float wy, float wz, float ww) {
    int node = wv;
    int rs0 = rowstart[node], rs1 = rowstart[node + 1];
    float d = dis[node];
    ushort4 sv = *(const ushort4*)(g + ((long)node << 4) + (fl << 2));
    int c0 = csr[min(rs0 + slot, etot - 1)];
    int c1 = csr[min(rs0 + slot + 16, etot - 1)];

    for (;;) {
        const int nnext = node + NW;
        const bool has_next = nnext < n;

        int rs0n, rs1n; float dn; ushort4 svn;
        if (has_next) {
            rs0n = rowstart[nnext];
            rs1n = rowstart[nnext + 1];
            dn = dis[nnext];
            svn = *(const ushort4*)(g + ((long)nnext << 4) + (fl << 2));
        }

        float a0 = 0.f, a1 = 0.f, a2 = 0.f, a3 = 0.f;
        if (rs0 + slot < rs1) {
            ushort4 v1 = *(const ushort4*)(g + ((long)c0 << 4) + (fl << 2));
            a0 += bf2f(v1.x); a1 += bf2f(v1.y); a2 += bf2f(v1.z); a3 += bf2f(v1.w);
        }
        if (rs0 + slot + 16 < rs1) {
            ushort4 v2 = *(const ushort4*)(g + ((long)c1 << 4) + (fl << 2));
            a0 += bf2f(v2.x); a1 += bf2f(v2.y); a2 += bf2f(v2.z); a3 += bf2f(v2.w);
        }
        for (int e2 = rs0 + slot + 32; e2 < rs1; e2 += 16) {
            int s1 = csr[e2];
            ushort4 v = *(const ushort4*)(g + ((long)s1 << 4) + (fl << 2));
            a0 += bf2f(v.x); a1 += bf2f(v.y); a2 += bf2f(v.z); a3 += bf2f(v.w);
        }

#pragma unroll
        for (int off = 4; off < 64; off <<= 1) {
            a0 += __shfl_xor(a0, off);
            a1 += __shfl_xor(a1, off);
            a2 += __shfl_xor(a2, off);
            a3 += __shfl_xor(a3, off);
        }
        a0 = (a0 + bf2f(sv.x)) * d;
        a1 = (a1 + bf2f(sv.y)) * d;
        a2 = (a2 + bf2f(sv.z)) * d;
        a3 = (a3 + bf2f(sv.w)) * d;
        float p = a0 * a0 * wx + a1 * a1 * wy + a2 * a2 * wz + a3 * a3 * ww;
        p += __shfl_xor(p, 1);
        p += __shfl_xor(p, 2);
        float inv = 1.0f / (sqrtf(p + 0.01f) + 0.01f);
        float h0 = a0 * inv, h1 = a1 * inv, h2 = a2 * inv, h3 = a3 * inv;
        if (slot == 0) {
            long base = ((long)node << 4) + (fl << 2);
            float4 hv = *(const float4*)(hidden + base);
            hv.x = fmaf(tk, h0, hv.x);
            hv.y = fmaf(tk, h1, hv.y);
            hv.z = fmaf(tk, h2, hv.z);
            hv.w = fmaf(tk, h3, hv.w);
            *(float4*)(hidden + base) = hv;
            if (writeg) {
                ushort4 o;
                o.x = f2bf(d * h0); o.y = f2bf(d * h1);
                o.z = f2bf(d * h2); o.w = f2bf(d * h3);
                *(ushort4*)(gn + base) = o;
            }
        }

        if (!has_next) break;

        int c0n = csr[min(rs0n + slot, etot - 1)];
        int c1n = csr[min(rs0n + slot + 16, etot - 1)];

        node = nnext;
        rs0 = rs0n; rs1 = rs1n; d = dn; sv = svn;
        c0 = c0n; c1 = c1n;
    }
}

// coop version: all K hops, one dispatch (counters become visible)
__global__ __launch_bounds__(256, 8) void hops_kernel(
    unsigned short* __restrict__ gA, unsigned short* __restrict__ gB,
    float* __restrict__ hidden, const float* __restrict__ dis,
    const int* __restrict__ rowstart, const int* __restrict__ csr,
    const float* __restrict__ temp, const float* __restrict__ wfn,
    int n, int etot) {
    cg::grid_group grid = cg::this_grid();
    const int wv = (blockIdx.x << 2) + (threadIdx.x >> 6);
    const int NW = gridDim.x << 2;
    const int lane = threadIdx.x & 63;
    const int slot = lane >> 2, fl = lane & 3;
    const float4 wq = *(const float4*)(wfn + (fl << 2));
    const float wx = fabsf(wq.x), wy = fabsf(wq.y),
                wz = fabsf(wq.z), ww = fabsf(wq.w);

    for (int k = 1; k <= K_HOPS; ++k) {
        const unsigned short* g = (k & 1) ? gA : gB;
        unsigned short* gn = (k & 1) ? gB : gA;
        if (wv < n)
            hop_sweeps(g, gn, hidden, dis, rowstart, csr, temp[k],
                       (k < K_HOPS) ? 1 : 0, n, etot, wv, NW, slot, fl,
                       wx, wy, wz, ww);
        __threadfence();
        grid.sync();
    }
}

// fallback: one launch per hop (r7 behavior)
__global__ __launch_bounds__(256) void hop_kernel(
    const unsigned short* __restrict__ g, unsigned short* __restrict__ gn,
    float* __restrict__ hidden, const float* __restrict__ dis,
    const int* __restrict__ rowstart, const int* __restrict__ csr,
    const float* __restrict__ temp, const float* __restrict__ wfn,
    int kidx, int writeg, int n, int etot) {
    const int wv = (blockIdx.x << 2) + (threadIdx.x >> 6);
    const int NW = gridDim.x << 2;
    if (wv >= n) return;
    const int lane = threadIdx.x & 63;
    const int slot = lane >> 2, fl = lane & 3;
    const float4 wq = *(const float4*)(wfn + (fl << 2));
    hop_sweeps(g, gn, hidden, dis, rowstart, csr, temp[kidx], writeg, n, etot,
               wv, NW, slot, fl, fabsf(wq.x), fabsf(wq.y), fabsf(wq.z),
               fabsf(wq.w));
}

// ---------------- launch ----------------

static inline long align4up(long w) { return (w + 3) & ~3L; }

extern "C" void kernel_launch(void* const* d_in, const int* in_sizes, int n_in,
                              void* d_out, int out_size, void* d_ws, size_t ws_size,
                              hipStream_t stream) {
    const float* x          = (const float*)d_in[0];
    const int*   edge_index = (const int*)d_in[1];
    const float* W1         = (const float*)d_in[2];
    const float* b1         = (const float*)d_in[3];
    const float* W2         = (const float*)d_in[4];
    const float* b2         = (const float*)d_in[5];
    const float* temp       = (const float*)d_in[6];
    const float* w_for_norm = (const float*)d_in[7];
    float* hidden = (float*)d_out;

    const int n = in_sizes[0] / F_IN;
    const int e = in_sizes[1] / 2;
    const int* rows = edge_index;        // sources
    const int* cols = edge_index + e;    // destinations
    const int nb = (n + BKT_NODES - 1) / BKT_NODES;

    long off = 0;
    int* wsI = (int*)d_ws;
    int* bcnt      = wsI + off; off = align4up(off + NBKT_MAX);
    int* bstart    = wsI + off; off = align4up(off + NBKT_MAX + 1);
    int* bcur      = wsI + off; off = align4up(off + NBKT_MAX);
    int* rowstart  = wsI + off; off = align4up(off + n + 1);
    float* dis     = (float*)(wsI + off); off = align4up(off + n);
    uint32* stage  = (uint32*)(wsI + off); off = align4up(off + e);
    int* csr       = wsI + off; off = align4up(off + e);
    unsigned short* w1t = (unsigned short*)(wsI + off); off = align4up(off + HD * F_IN / 2);
    unsigned short* w2t = (unsigned short*)(wsI + off); off = align4up(off + CD * HD / 2);
    unsigned short* gA  = (unsigned short*)(wsI + off); off = align4up(off + n * 8);
    unsigned short* gB  = (unsigned short*)(wsI + off); off = align4up(off + n * 8);

    const int B = 256;
    const int nbC = (e + EPB - 1) / EPB;

    zero_kernel<<<(nb + B - 1) / B, B, 0, stream>>>(bcnt, nb);
    bucket_hist_kernel<<<nbC, B, 0, stream>>>(cols, bcnt, e, nb);
    bucket_scan_kernel<<<1, B, 0, stream>>>(bcnt, bstart, bcur, nb);
    scatter_bin_kernel<<<nbC, B, 0, stream>>>(rows, cols, bcur, stage, e, nb);
    bucket_sort_kernel<<<nb, B, 0, stream>>>(stage, bstart, rowstart, dis, csr, n, e);
    convw_kernel<<<(HD * F_IN + CD * HD + B - 1) / B, B, 0, stream>>>(W1, W2, w1t, w2t);

    mlp_kernel<<<(n + 63) / 64, B, 0, stream>>>(x, w1t, b1, w2t, b2, dis, temp,
                                                w_for_norm, gA, hidden, n);

    {
        unsigned short* gA_ = gA;
        unsigned short* gB_ = gB;
        float* hidden_ = hidden;
        const float* dis_ = dis;
        const int* rowstart_ = rowstart;
        const int* csr_ = csr;
        const float* temp_ = temp;
        const float* wfn_ = w_for_norm;
        int n_ = n, e_ = e;
        void* args[] = {&gA_, &gB_, &hidden_, &dis_, &rowstart_, &csr_,
                        &temp_, &wfn_, &n_, &e_};
        hipError_t err = hipLaunchCooperativeKernel(
            (const void*)hops_kernel, dim3(HOP_BLOCKS), dim3(B), args, 0, stream);
        if (err != hipSuccess) {
            unsigned short* gsrc = gA;
            unsigned short* gdst = gB;
            for (int k = 1; k <= K_HOPS; ++k) {
                hop_kernel<<<HOP_BLOCKS, B, 0, stream>>>(
                    gsrc, gdst, hidden, dis, rowstart, csr, temp, w_for_norm,
                    k, (k < K_HOPS) ? 1 : 0, n, e);
                unsigned short* tmp = gsrc; gsrc = gdst; gdst = tmp;
            }
        }
    }
}

// Round 9
// 590.070 us; speedup vs baseline: 8.1215x; 8.1215x over previous
//
#include <hip/hip_runtime.h>
#include <hip/hip_fp16.h>
#include <math.h>

#define F_IN 512
#define HD 64
#define CD 16
#define K_HOPS 10

#define BKT_SHIFT 7
#define BKT_NODES 128
#define NBKT_MAX 1024
#define EPB 8192

#define HOP_BLOCKS 2048

typedef unsigned int uint32;
typedef __attribute__((ext_vector_type(8))) short short8v;
typedef __attribute__((ext_vector_type(8))) unsigned short ushort8v;
typedef __attribute__((ext_vector_type(4))) float float4v;

static __device__ __forceinline__ float bf2f(unsigned short h) {
    return __uint_as_float(((uint32)h) << 16);
}
static __device__ __forceinline__ unsigned short f2bf(float x) {
    uint32 u = __float_as_uint(x);
    u = (u + 0x7FFFu + ((u >> 16) & 1u)) >> 16;   // RNE
    return (unsigned short)u;
}

// ---------------- CSR build: two-level bucket sort ----------------

__global__ void zero_kernel(int* __restrict__ p, int n) {
    int i = blockIdx.x * blockDim.x + threadIdx.x;
    if (i < n) p[i] = 0;
}

__global__ __launch_bounds__(256) void bucket_hist_kernel(
    const int* __restrict__ cols, int* __restrict__ bcnt, int e, int nb) {
    __shared__ int c[NBKT_MAX];
    int t = threadIdx.x;
    for (int i = t; i < nb; i += 256) c[i] = 0;
    __syncthreads();
    int base = blockIdx.x * EPB;
    int end = min(base + EPB, e);
    for (int i = base + t; i < end; i += 256)
        atomicAdd(&c[cols[i] >> BKT_SHIFT], 1);
    __syncthreads();
    for (int i = t; i < nb; i += 256)
        if (c[i]) atomicAdd(&bcnt[i], c[i]);
}

__global__ __launch_bounds__(256) void bucket_scan_kernel(
    const int* __restrict__ bcnt, int* __restrict__ bstart,
    int* __restrict__ bcur, int nb) {
    __shared__ int s[256];
    int t = threadIdx.x;
    int v[4]; int sum = 0;
#pragma unroll
    for (int i = 0; i < 4; ++i) {
        int idx = t * 4 + i;
        v[i] = (idx < nb) ? bcnt[idx] : 0;
        sum += v[i];
    }
    s[t] = sum; __syncthreads();
    for (int off = 1; off < 256; off <<= 1) {
        int x = (t >= off) ? s[t - off] : 0;
        __syncthreads();
        s[t] += x;
        __syncthreads();
    }
    int excl = s[t] - sum;
#pragma unroll
    for (int i = 0; i < 4; ++i) {
        int idx = t * 4 + i;
        if (idx < nb) { bstart[idx] = excl; bcur[idx] = excl; }
        excl += v[i];
    }
    if (t == 255) bstart[nb] = excl;
}

__global__ __launch_bounds__(256) void scatter_bin_kernel(
    const int* __restrict__ rows, const int* __restrict__ cols,
    int* __restrict__ bcur, uint32* __restrict__ stage, int e, int nb) {
    __shared__ int c[NBKT_MAX];
    int t = threadIdx.x;
    for (int i = t; i < nb; i += 256) c[i] = 0;
    __syncthreads();
    int base = blockIdx.x * EPB;
    int end = min(base + EPB, e);
    for (int i = base + t; i < end; i += 256)
        atomicAdd(&c[cols[i] >> BKT_SHIFT], 1);
    __syncthreads();
    for (int i = t; i < nb; i += 256) {
        int cc = c[i];
        if (cc) c[i] = atomicAdd(&bcur[i], cc);
    }
    __syncthreads();
    for (int i = base + t; i < end; i += 256) {
        int col = cols[i];
        int b = col >> BKT_SHIFT;
        int pos = atomicAdd(&c[b], 1);
        stage[pos] = ((uint32)rows[i] << BKT_SHIFT) | (uint32)(col & (BKT_NODES - 1));
    }
}

__global__ __launch_bounds__(256) void bucket_sort_kernel(
    const uint32* __restrict__ stage, const int* __restrict__ bstart,
    int* __restrict__ rowstart, float* __restrict__ dis,
    int* __restrict__ csr, int n, int e) {
    __shared__ int cnt[BKT_NODES];
    __shared__ int excl[BKT_NODES];
    __shared__ int lcur[BKT_NODES];
    int b = blockIdx.x, t = threadIdx.x;
    int s0 = bstart[b], s1 = bstart[b + 1];
    int nnode = min(BKT_NODES, n - b * BKT_NODES);
    if (t < BKT_NODES) cnt[t] = 0;
    __syncthreads();
    for (int i = s0 + t; i < s1; i += 256)
        atomicAdd(&cnt[stage[i] & (BKT_NODES - 1)], 1);
    __syncthreads();
    if (t < BKT_NODES) excl[t] = cnt[t];
    __syncthreads();
    for (int off = 1; off < BKT_NODES; off <<= 1) {
        int x = 0;
        if (t < BKT_NODES && t >= off) x = excl[t - off];
        __syncthreads();
        if (t < BKT_NODES) excl[t] += x;
        __syncthreads();
    }
    if (t < BKT_NODES) {
        int rs = s0 + excl[t] - cnt[t];
        lcur[t] = rs;
        if (t < nnode) {
            rowstart[b * BKT_NODES + t] = rs;
            dis[b * BKT_NODES + t] = rsqrtf((float)(cnt[t] + 1));
        }
    }
    if (b == 0 && t == 0) rowstart[n] = e;
    __syncthreads();
    for (int i = s0 + t; i < s1; i += 256) {
        uint32 v = stage[i];
        int pos = atomicAdd(&lcur[v & (BKT_NODES - 1)], 1);
        csr[pos] = (int)(v >> BKT_SHIFT);
    }
}

// ---------------- weight transpose + bf16 convert (one-time) -------------

__global__ void convw_kernel(const float* __restrict__ W1,
                             const float* __restrict__ W2,
                             unsigned short* __restrict__ w1t,
                             unsigned short* __restrict__ w2t) {
    int i = blockIdx.x * blockDim.x + threadIdx.x;
    if (i < HD * F_IN) {
        int h = i >> 9, k = i & 511;
        w1t[i] = f2bf(W1[k * HD + h]);
    } else {
        int j = i - HD * F_IN;
        if (j < CD * HD) {
            int c = j >> 6, k = j & 63;
            w2t[j] = f2bf(W2[k * CD + c]);
        }
    }
}

// ---------------- MFMA MLP + riemann + init ------------------------------

#define LSTR 72

__global__ __launch_bounds__(256) void mlp_kernel(
    const float* __restrict__ x, const unsigned short* __restrict__ w1t,
    const float* __restrict__ b1, const unsigned short* __restrict__ w2t,
    const float* __restrict__ b2, const float* __restrict__ dis,
    const float* __restrict__ temp, const float* __restrict__ wfn,
    unsigned short* __restrict__ g0, float* __restrict__ hidden, int n) {
    __shared__ __align__(16) unsigned short xb[64 * LSTR];
    __shared__ __align__(16) unsigned short w1b[64 * LSTR];
    __shared__ __align__(16) unsigned short w2b[16 * LSTR];

    const int t = threadIdx.x;
    const int row0 = blockIdx.x * 64;
    const int wave = t >> 6, lane = t & 63;
    const int l15 = lane & 15, lq = lane >> 4;
    const int lrow = (wave << 4) + l15;

    if (t < 128) {
        int cr = t >> 3, part = t & 7;
        *(short8v*)&w2b[cr * LSTR + part * 8] =
            *(const short8v*)&w2t[cr * HD + part * 8];
    }

    float4v acc[4];
#pragma unroll
    for (int i = 0; i < 4; ++i) acc[i] = (float4v)0.0f;

    const int srow = t >> 2, spart = t & 3;
    for (int c = 0; c < F_IN / 64; ++c) {
        __syncthreads();
        {
            int gr = row0 + srow; if (gr >= n) gr = n - 1;
            const float* xp = x + (long)gr * F_IN + c * 64 + spart * 16;
            float4 v0 = *(const float4*)(xp + 0);
            float4 v1 = *(const float4*)(xp + 4);
            float4 v2 = *(const float4*)(xp + 8);
            float4 v3 = *(const float4*)(xp + 12);
            short8v o0, o1;
            o0[0] = (short)f2bf(v0.x); o0[1] = (short)f2bf(v0.y);
            o0[2] = (short)f2bf(v0.z); o0[3] = (short)f2bf(v0.w);
            o0[4] = (short)f2bf(v1.x); o0[5] = (short)f2bf(v1.y);
            o0[6] = (short)f2bf(v1.z); o0[7] = (short)f2bf(v1.w);
            o1[0] = (short)f2bf(v2.x); o1[1] = (short)f2bf(v2.y);
            o1[2] = (short)f2bf(v2.z); o1[3] = (short)f2bf(v2.w);
            o1[4] = (short)f2bf(v3.x); o1[5] = (short)f2bf(v3.y);
            o1[6] = (short)f2bf(v3.z); o1[7] = (short)f2bf(v3.w);
            *(short8v*)&xb[srow * LSTR + spart * 16] = o0;
            *(short8v*)&xb[srow * LSTR + spart * 16 + 8] = o1;
            const unsigned short* wp = w1t + srow * F_IN + c * 64 + spart * 16;
            *(short8v*)&w1b[srow * LSTR + spart * 16] = *(const short8v*)(wp);
            *(short8v*)&w1b[srow * LSTR + spart * 16 + 8] = *(const short8v*)(wp + 8);
        }
        __syncthreads();
#pragma unroll
        for (int st = 0; st < 2; ++st) {
            int kb = st * 32 + lq * 8;
            short8v av = *(const short8v*)&xb[lrow * LSTR + kb];
#pragma unroll
            for (int hf = 0; hf < 4; ++hf) {
                short8v bv = *(const short8v*)&w1b[(hf * 16 + l15) * LSTR + kb];
                acc[hf] = __builtin_amdgcn_mfma_f32_16x16x32_bf16(av, bv, acc[hf], 0, 0, 0);
            }
        }
    }

    __syncthreads();
    {
        int drow = (wave << 4) + (lq << 2);
#pragma unroll
        for (int hf = 0; hf < 4; ++hf) {
            int h = hf * 16 + l15;
            float bv = b1[h];
#pragma unroll
            for (int i = 0; i < 4; ++i) {
                float v = acc[hf][i] + bv;
                v = v > 0.0f ? v : 0.0f;
                xb[(drow + i) * LSTR + h] = f2bf(v);
            }
        }
    }
    __syncthreads();

    float4v acc2 = (float4v)0.0f;
#pragma unroll
    for (int st = 0; st < 2; ++st) {
        int kb = st * 32 + lq * 8;
        short8v av = *(const short8v*)&xb[lrow * LSTR + kb];
        short8v bv = *(const short8v*)&w2b[l15 * LSTR + kb];
        acc2 = __builtin_amdgcn_mfma_f32_16x16x32_bf16(av, bv, acc2, 0, 0, 0);
    }

    {
        const int cc = l15;
        const int drow = (wave << 4) + (lq << 2);
        float b2c = b2[cc];
        float wabs = fabsf(wfn[cc]);
        float o[4], p[4];
#pragma unroll
        for (int i = 0; i < 4; ++i) {
            o[i] = acc2[i] + b2c;
            p[i] = o[i] * o[i] * wabs;
        }
#pragma unroll
        for (int off = 1; off < 16; off <<= 1) {
#pragma unroll
            for (int i = 0; i < 4; ++i) p[i] += __shfl_xor(p[i], off);
        }
        float t0 = temp[0];
#pragma unroll
        for (int i = 0; i < 4; ++i) {
            int grow = row0 + drow + i;
            if (grow < n) {
                float inv = 1.0f / (sqrtf(p[i] + 0.01f) + 0.01f);
                float hn = o[i] * inv;
                float d = dis[grow];
                hidden[(long)grow * CD + cc] = t0 * hn;
                g0[(long)grow * CD + cc] = f2bf(d * hn);
            }
        }
    }
}

// ---------------- fused hop: wave/node, 32 edge-slots x 2 half-rows ------
// 16B gathers (2 requests/edge vs 4), depth-1 next-node pipeline, f16x2
// packed butterfly (20 bpermutes vs 40 f32).

__global__ __launch_bounds__(256) void hop_kernel(
    const unsigned short* __restrict__ g, unsigned short* __restrict__ gn,
    float* __restrict__ hidden, const float* __restrict__ dis,
    const int* __restrict__ rowstart, const int* __restrict__ csr,
    const float* __restrict__ temp, const float* __restrict__ wfn,
    int kidx, int writeg, int n, int etot) {
    const int wv = (blockIdx.x << 2) + (threadIdx.x >> 6);
    const int NW = gridDim.x << 2;
    if (wv >= n) return;
    const int lane = threadIdx.x & 63;
    const int slot = lane >> 1, fl = lane & 1;   // 32 slots x 2 half-rows
    const float tk = temp[kidx];

    float w8[8];
    {
        float4 wa = *(const float4*)(wfn + (fl << 3));
        float4 wb = *(const float4*)(wfn + (fl << 3) + 4);
        w8[0] = fabsf(wa.x); w8[1] = fabsf(wa.y);
        w8[2] = fabsf(wa.z); w8[3] = fabsf(wa.w);
        w8[4] = fabsf(wb.x); w8[5] = fabsf(wb.y);
        w8[6] = fabsf(wb.z); w8[7] = fabsf(wb.w);
    }

    // prologue: first node
    int node = wv;
    int rs0 = rowstart[node], rs1 = rowstart[node + 1];
    float d = dis[node];
    ushort8v sv = *(const ushort8v*)(g + ((long)node << 4) + (fl << 3));
    int c0 = csr[min(rs0 + slot, etot - 1)];

    for (;;) {
        const int nnext = node + NW;
        const bool has_next = nnext < n;

        // (1) next node's independent loads
        int rs0n, rs1n; float dn; ushort8v svn;
        if (has_next) {
            rs0n = rowstart[nnext];
            rs1n = rowstart[nnext + 1];
            dn = dis[nnext];
            svn = *(const ushort8v*)(g + ((long)nnext << 4) + (fl << 3));
        }

        // (2) gather: 32 edges/round, 16B per lane
        float a[8];
#pragma unroll
        for (int j = 0; j < 8; ++j) a[j] = 0.0f;
        if (rs0 + slot < rs1) {
            ushort8v v = *(const ushort8v*)(g + ((long)c0 << 4) + (fl << 3));
#pragma unroll
            for (int j = 0; j < 8; ++j) a[j] += bf2f(v[j]);
        }
        for (int e2 = rs0 + slot + 32; e2 < rs1; e2 += 32) {
            int s1 = csr[e2];
            ushort8v v = *(const ushort8v*)(g + ((long)s1 << 4) + (fl << 3));
#pragma unroll
            for (int j = 0; j < 8; ++j) a[j] += bf2f(v[j]);
        }

        // (3) butterfly over 32 slots, packed f16x2
        {
            unsigned int pk[4];
#pragma unroll
            for (int i = 0; i < 4; ++i) {
                __half2 hh = __floats2half2_rn(a[2 * i], a[2 * i + 1]);
                pk[i] = *(unsigned int*)&hh;
            }
#pragma unroll
            for (int off = 2; off < 64; off <<= 1) {
#pragma unroll
                for (int i = 0; i < 4; ++i) {
                    unsigned int o = (unsigned int)__shfl_xor((int)pk[i], off);
                    __half2 s = *(__half2*)&pk[i] + *(__half2*)&o;
                    pk[i] = *(unsigned int*)&s;
                }
            }
#pragma unroll
            for (int i = 0; i < 4; ++i) {
                float2 f = __half22float2(*(__half2*)&pk[i]);
                a[2 * i] = f.x;
                a[2 * i + 1] = f.y;
            }
        }

        // (4) self-loop + dis scale + riemann
#pragma unroll
        for (int j = 0; j < 8; ++j) a[j] = (a[j] + bf2f(sv[j])) * d;
        float p = 0.0f;
#pragma unroll
        for (int j = 0; j < 8; ++j) p += a[j] * a[j] * w8[j];
        p += __shfl_xor(p, 1);
        float inv = 1.0f / (sqrtf(p + 0.01f) + 0.01f);

        // (5) writes (2 lanes per node: slot 0, fl 0/1)
        if (slot == 0) {
            long base = ((long)node << 4) + (fl << 3);
            float4 h0 = *(const float4*)(hidden + base);
            float4 h1 = *(const float4*)(hidden + base + 4);
            h0.x = fmaf(tk, a[0] * inv, h0.x);
            h0.y = fmaf(tk, a[1] * inv, h0.y);
            h0.z = fmaf(tk, a[2] * inv, h0.z);
            h0.w = fmaf(tk, a[3] * inv, h0.w);
            h1.x = fmaf(tk, a[4] * inv, h1.x);
            h1.y = fmaf(tk, a[5] * inv, h1.y);
            h1.z = fmaf(tk, a[6] * inv, h1.z);
            h1.w = fmaf(tk, a[7] * inv, h1.w);
            *(float4*)(hidden + base) = h0;
            *(float4*)(hidden + base + 4) = h1;
            if (writeg) {
                ushort8v o;
#pragma unroll
                for (int j = 0; j < 8; ++j) o[j] = f2bf(d * a[j] * inv);
                *(ushort8v*)(gn + base) = o;
            }
        }

        if (!has_next) break;

        // (6) prefetch next node's first-round csr
        int c0n = csr[min(rs0n + slot, etot - 1)];

        // (7) rotate
        node = nnext;
        rs0 = rs0n; rs1 = rs1n; d = dn; sv = svn; c0 = c0n;
    }
}

// ---------------- launch ----------------

static inline long align4up(long w) { return (w + 3) & ~3L; }

extern "C" void kernel_launch(void* const* d_in, const int* in_sizes, int n_in,
                              void* d_out, int out_size, void* d_ws, size_t ws_size,
                              hipStream_t stream) {
    const float* x          = (const float*)d_in[0];
    const int*   edge_index = (const int*)d_in[1];
    const float* W1         = (const float*)d_in[2];
    const float* b1         = (const float*)d_in[3];
    const float* W2         = (const float*)d_in[4];
    const float* b2         = (const float*)d_in[5];
    const float* temp       = (const float*)d_in[6];
    const float* w_for_norm = (const float*)d_in[7];
    float* hidden = (float*)d_out;

    const int n = in_sizes[0] / F_IN;
    const int e = in_sizes[1] / 2;
    const int* rows = edge_index;        // sources
    const int* cols = edge_index + e;    // destinations
    const int nb = (n + BKT_NODES - 1) / BKT_NODES;

    long off = 0;
    int* wsI = (int*)d_ws;
    int* bcnt      = wsI + off; off = align4up(off + NBKT_MAX);
    int* bstart    = wsI + off; off = align4up(off + NBKT_MAX + 1);
    int* bcur      = wsI + off; off = align4up(off + NBKT_MAX);
    int* rowstart  = wsI + off; off = align4up(off + n + 1);
    float* dis     = (float*)(wsI + off); off = align4up(off + n);
    uint32* stage  = (uint32*)(wsI + off); off = align4up(off + e);
    int* csr       = wsI + off; off = align4up(off + e);
    unsigned short* w1t = (unsigned short*)(wsI + off); off = align4up(off + HD * F_IN / 2);
    unsigned short* w2t = (unsigned short*)(wsI + off); off = align4up(off + CD * HD / 2);
    unsigned short* gA  = (unsigned short*)(wsI + off); off = align4up(off + n * 8);
    unsigned short* gB  = (unsigned short*)(wsI + off); off = align4up(off + n * 8);

    const int B = 256;
    const int nbC = (e + EPB - 1) / EPB;

    zero_kernel<<<(nb + B - 1) / B, B, 0, stream>>>(bcnt, nb);
    bucket_hist_kernel<<<nbC, B, 0, stream>>>(cols, bcnt, e, nb);
    bucket_scan_kernel<<<1, B, 0, stream>>>(bcnt, bstart, bcur, nb);
    scatter_bin_kernel<<<nbC, B, 0, stream>>>(rows, cols, bcur, stage, e, nb);
    bucket_sort_kernel<<<nb, B, 0, stream>>>(stage, bstart, rowstart, dis, csr, n, e);
    convw_kernel<<<(HD * F_IN + CD * HD + B - 1) / B, B, 0, stream>>>(W1, W2, w1t, w2t);

    mlp_kernel<<<(n + 63) / 64, B, 0, stream>>>(x, w1t, b1, w2t, b2, dis, temp,
                                                w_for_norm, gA, hidden, n);

    unsigned short* gsrc = gA;
    unsigned short* gdst = gB;
    for (int k = 1; k <= K_HOPS; ++k) {
        hop_kernel<<<HOP_BLOCKS, B, 0, stream>>>(
            gsrc, gdst, hidden, dis, rowstart, csr, temp, w_for_norm,
            k, (k < K_HOPS) ? 1 : 0, n, e);
        unsigned short* tmp = gsrc; gsrc = gdst; gdst = tmp;
    }
}

// Round 10
// 547.673 us; speedup vs baseline: 8.7502x; 1.0774x over previous
//
#include <hip/hip_runtime.h>
#include <hip/hip_fp16.h>
#include <math.h>

#define F_IN 512
#define HD 64
#define CD 16
#define K_HOPS 10

#define BKT_SHIFT 7
#define BKT_NODES 128
#define NBKT_MAX 1024
#define EPB 8192

#define HOP_BLOCKS 2048

typedef unsigned int uint32;
typedef __attribute__((ext_vector_type(8))) short short8v;
typedef __attribute__((ext_vector_type(4))) float float4v;
typedef __attribute__((ext_vector_type(2))) float float2v;

static __device__ __forceinline__ float bf2f(unsigned short h) {
    return __uint_as_float(((uint32)h) << 16);
}
static __device__ __forceinline__ unsigned short f2bf(float x) {
    uint32 u = __float_as_uint(x);
    u = (u + 0x7FFFu + ((u >> 16) & 1u)) >> 16;   // RNE
    return (unsigned short)u;
}

// fp8 e4m3 (OCP on gfx950) helpers
static __device__ __forceinline__ void fp8x8_acc(uint2 v, float* a) {
    float2v f;
    f = __builtin_amdgcn_cvt_pk_f32_fp8(v.x, false); a[0] += f[0]; a[1] += f[1];
    f = __builtin_amdgcn_cvt_pk_f32_fp8(v.x, true);  a[2] += f[0]; a[3] += f[1];
    f = __builtin_amdgcn_cvt_pk_f32_fp8(v.y, false); a[4] += f[0]; a[5] += f[1];
    f = __builtin_amdgcn_cvt_pk_f32_fp8(v.y, true);  a[6] += f[0]; a[7] += f[1];
}
static __device__ __forceinline__ unsigned int fp8pk4(float a, float b, float c, float d) {
    unsigned int u = (unsigned int)__builtin_amdgcn_cvt_pk_fp8_f32(a, b, 0, false);
    u = (unsigned int)__builtin_amdgcn_cvt_pk_fp8_f32(c, d, (int)u, true);
    return u;
}
static __device__ __forceinline__ unsigned char fp8one(float v) {
    return (unsigned char)((unsigned int)__builtin_amdgcn_cvt_pk_fp8_f32(v, v, 0, false) & 0xFFu);
}

// ---------------- CSR build: two-level bucket sort ----------------

__global__ void zero_kernel(int* __restrict__ p, int n) {
    int i = blockIdx.x * blockDim.x + threadIdx.x;
    if (i < n) p[i] = 0;
}

__global__ __launch_bounds__(256) void bucket_hist_kernel(
    const int* __restrict__ cols, int* __restrict__ bcnt, int e, int nb) {
    __shared__ int c[NBKT_MAX];
    int t = threadIdx.x;
    for (int i = t; i < nb; i += 256) c[i] = 0;
    __syncthreads();
    int base = blockIdx.x * EPB;
    int end = min(base + EPB, e);
    for (int i = base + t; i < end; i += 256)
        atomicAdd(&c[cols[i] >> BKT_SHIFT], 1);
    __syncthreads();
    for (int i = t; i < nb; i += 256)
        if (c[i]) atomicAdd(&bcnt[i], c[i]);
}

__global__ __launch_bounds__(256) void bucket_scan_kernel(
    const int* __restrict__ bcnt, int* __restrict__ bstart,
    int* __restrict__ bcur, int nb) {
    __shared__ int s[256];
    int t = threadIdx.x;
    int v[4]; int sum = 0;
#pragma unroll
    for (int i = 0; i < 4; ++i) {
        int idx = t * 4 + i;
        v[i] = (idx < nb) ? bcnt[idx] : 0;
        sum += v[i];
    }
    s[t] = sum; __syncthreads();
    for (int off = 1; off < 256; off <<= 1) {
        int x = (t >= off) ? s[t - off] : 0;
        __syncthreads();
        s[t] += x;
        __syncthreads();
    }
    int excl = s[t] - sum;
#pragma unroll
    for (int i = 0; i < 4; ++i) {
        int idx = t * 4 + i;
        if (idx < nb) { bstart[idx] = excl; bcur[idx] = excl; }
        excl += v[i];
    }
    if (t == 255) bstart[nb] = excl;
}

__global__ __launch_bounds__(256) void scatter_bin_kernel(
    const int* __restrict__ rows, const int* __restrict__ cols,
    int* __restrict__ bcur, uint32* __restrict__ stage, int e, int nb) {
    __shared__ int c[NBKT_MAX];
    int t = threadIdx.x;
    for (int i = t; i < nb; i += 256) c[i] = 0;
    __syncthreads();
    int base = blockIdx.x * EPB;
    int end = min(base + EPB, e);
    for (int i = base + t; i < end; i += 256)
        atomicAdd(&c[cols[i] >> BKT_SHIFT], 1);
    __syncthreads();
    for (int i = t; i < nb; i += 256) {
        int cc = c[i];
        if (cc) c[i] = atomicAdd(&bcur[i], cc);
    }
    __syncthreads();
    for (int i = base + t; i < end; i += 256) {
        int col = cols[i];
        int b = col >> BKT_SHIFT;
        int pos = atomicAdd(&c[b], 1);
        stage[pos] = ((uint32)rows[i] << BKT_SHIFT) | (uint32)(col & (BKT_NODES - 1));
    }
}

__global__ __launch_bounds__(256) void bucket_sort_kernel(
    const uint32* __restrict__ stage, const int* __restrict__ bstart,
    int* __restrict__ rowstart, float* __restrict__ dis,
    int* __restrict__ csr, int n, int e) {
    __shared__ int cnt[BKT_NODES];
    __shared__ int excl[BKT_NODES];
    __shared__ int lcur[BKT_NODES];
    int b = blockIdx.x, t = threadIdx.x;
    int s0 = bstart[b], s1 = bstart[b + 1];
    int nnode = min(BKT_NODES, n - b * BKT_NODES);
    if (t < BKT_NODES) cnt[t] = 0;
    __syncthreads();
    for (int i = s0 + t; i < s1; i += 256)
        atomicAdd(&cnt[stage[i] & (BKT_NODES - 1)], 1);
    __syncthreads();
    if (t < BKT_NODES) excl[t] = cnt[t];
    __syncthreads();
    for (int off = 1; off < BKT_NODES; off <<= 1) {
        int x = 0;
        if (t < BKT_NODES && t >= off) x = excl[t - off];
        __syncthreads();
        if (t < BKT_NODES) excl[t] += x;
        __syncthreads();
    }
    if (t < BKT_NODES) {
        int rs = s0 + excl[t] - cnt[t];
        lcur[t] = rs;
        if (t < nnode) {
            rowstart[b * BKT_NODES + t] = rs;
            dis[b * BKT_NODES + t] = rsqrtf((float)(cnt[t] + 1));
        }
    }
    if (b == 0 && t == 0) rowstart[n] = e;
    __syncthreads();
    for (int i = s0 + t; i < s1; i += 256) {
        uint32 v = stage[i];
        int pos = atomicAdd(&lcur[v & (BKT_NODES - 1)], 1);
        csr[pos] = (int)(v >> BKT_SHIFT);
    }
}

// ---------------- weight transpose + bf16 convert (one-time) -------------

__global__ void convw_kernel(const float* __restrict__ W1,
                             const float* __restrict__ W2,
                             unsigned short* __restrict__ w1t,
                             unsigned short* __restrict__ w2t) {
    int i = blockIdx.x * blockDim.x + threadIdx.x;
    if (i < HD * F_IN) {
        int h = i >> 9, k = i & 511;
        w1t[i] = f2bf(W1[k * HD + h]);
    } else {
        int j = i - HD * F_IN;
        if (j < CD * HD) {
            int c = j >> 6, k = j & 63;
            w2t[j] = f2bf(W2[k * CD + c]);
        }
    }
}

// ---------------- MFMA MLP + riemann + init ------------------------------

#define LSTR 72

__global__ __launch_bounds__(256) void mlp_kernel(
    const float* __restrict__ x, const unsigned short* __restrict__ w1t,
    const float* __restrict__ b1, const unsigned short* __restrict__ w2t,
    const float* __restrict__ b2, const float* __restrict__ dis,
    const float* __restrict__ temp, const float* __restrict__ wfn,
    unsigned char* __restrict__ g0, float* __restrict__ hidden, int n) {
    __shared__ __align__(16) unsigned short xb[64 * LSTR];
    __shared__ __align__(16) unsigned short w1b[64 * LSTR];
    __shared__ __align__(16) unsigned short w2b[16 * LSTR];

    const int t = threadIdx.x;
    const int row0 = blockIdx.x * 64;
    const int wave = t >> 6, lane = t & 63;
    const int l15 = lane & 15, lq = lane >> 4;
    const int lrow = (wave << 4) + l15;

    if (t < 128) {
        int cr = t >> 3, part = t & 7;
        *(short8v*)&w2b[cr * LSTR + part * 8] =
            *(const short8v*)&w2t[cr * HD + part * 8];
    }

    float4v acc[4];
#pragma unroll
    for (int i = 0; i < 4; ++i) acc[i] = (float4v)0.0f;

    const int srow = t >> 2, spart = t & 3;
    for (int c = 0; c < F_IN / 64; ++c) {
        __syncthreads();
        {
            int gr = row0 + srow; if (gr >= n) gr = n - 1;
            const float* xp = x + (long)gr * F_IN + c * 64 + spart * 16;
            float4 v0 = *(const float4*)(xp + 0);
            float4 v1 = *(const float4*)(xp + 4);
            float4 v2 = *(const float4*)(xp + 8);
            float4 v3 = *(const float4*)(xp + 12);
            short8v o0, o1;
            o0[0] = (short)f2bf(v0.x); o0[1] = (short)f2bf(v0.y);
            o0[2] = (short)f2bf(v0.z); o0[3] = (short)f2bf(v0.w);
            o0[4] = (short)f2bf(v1.x); o0[5] = (short)f2bf(v1.y);
            o0[6] = (short)f2bf(v1.z); o0[7] = (short)f2bf(v1.w);
            o1[0] = (short)f2bf(v2.x); o1[1] = (short)f2bf(v2.y);
            o1[2] = (short)f2bf(v2.z); o1[3] = (short)f2bf(v2.w);
            o1[4] = (short)f2bf(v3.x); o1[5] = (short)f2bf(v3.y);
            o1[6] = (short)f2bf(v3.z); o1[7] = (short)f2bf(v3.w);
            *(short8v*)&xb[srow * LSTR + spart * 16] = o0;
            *(short8v*)&xb[srow * LSTR + spart * 16 + 8] = o1;
            const unsigned short* wp = w1t + srow * F_IN + c * 64 + spart * 16;
            *(short8v*)&w1b[srow * LSTR + spart * 16] = *(const short8v*)(wp);
            *(short8v*)&w1b[srow * LSTR + spart * 16 + 8] = *(const short8v*)(wp + 8);
        }
        __syncthreads();
#pragma unroll
        for (int st = 0; st < 2; ++st) {
            int kb = st * 32 + lq * 8;
            short8v av = *(const short8v*)&xb[lrow * LSTR + kb];
#pragma unroll
            for (int hf = 0; hf < 4; ++hf) {
                short8v bv = *(const short8v*)&w1b[(hf * 16 + l15) * LSTR + kb];
                acc[hf] = __builtin_amdgcn_mfma_f32_16x16x32_bf16(av, bv, acc[hf], 0, 0, 0);
            }
        }
    }

    __syncthreads();
    {
        int drow = (wave << 4) + (lq << 2);
#pragma unroll
        for (int hf = 0; hf < 4; ++hf) {
            int h = hf * 16 + l15;
            float bv = b1[h];
#pragma unroll
            for (int i = 0; i < 4; ++i) {
                float v = acc[hf][i] + bv;
                v = v > 0.0f ? v : 0.0f;
                xb[(drow + i) * LSTR + h] = f2bf(v);
            }
        }
    }
    __syncthreads();

    float4v acc2 = (float4v)0.0f;
#pragma unroll
    for (int st = 0; st < 2; ++st) {
        int kb = st * 32 + lq * 8;
        short8v av = *(const short8v*)&xb[lrow * LSTR + kb];
        short8v bv = *(const short8v*)&w2b[l15 * LSTR + kb];
        acc2 = __builtin_amdgcn_mfma_f32_16x16x32_bf16(av, bv, acc2, 0, 0, 0);
    }

    {
        const int cc = l15;
        const int drow = (wave << 4) + (lq << 2);
        float b2c = b2[cc];
        float wabs = fabsf(wfn[cc]);
        float o[4], p[4];
#pragma unroll
        for (int i = 0; i < 4; ++i) {
            o[i] = acc2[i] + b2c;
            p[i] = o[i] * o[i] * wabs;
        }
#pragma unroll
        for (int off = 1; off < 16; off <<= 1) {
#pragma unroll
            for (int i = 0; i < 4; ++i) p[i] += __shfl_xor(p[i], off);
        }
        float t0 = temp[0];
#pragma unroll
        for (int i = 0; i < 4; ++i) {
            int grow = row0 + drow + i;
            if (grow < n) {
                float inv = 1.0f / (sqrtf(p[i] + 0.01f) + 0.01f);
                float hn = o[i] * inv;
                float d = dis[grow];
                hidden[(long)grow * CD + cc] = t0 * hn;
                g0[(long)grow * CD + cc] = fp8one(d * hn);
            }
        }
    }
}

// ---------------- fused hop: wave/node, 32 slots x 2 half-rows, fp8 g ----
// 8B gathers (2 beats/edge vs bf16's 4), depth-1 next-node pipeline,
// f16x2 packed butterfly (r9-verified numerics).

__global__ __launch_bounds__(256) void hop_kernel(
    const unsigned char* __restrict__ g, unsigned char* __restrict__ gn,
    float* __restrict__ hidden, const float* __restrict__ dis,
    const int* __restrict__ rowstart, const int* __restrict__ csr,
    const float* __restrict__ temp, const float* __restrict__ wfn,
    int kidx, int writeg, int n, int etot) {
    const int wv = (blockIdx.x << 2) + (threadIdx.x >> 6);
    const int NW = gridDim.x << 2;
    if (wv >= n) return;
    const int lane = threadIdx.x & 63;
    const int slot = lane >> 1, fl = lane & 1;   // 32 slots x 2 half-rows
    const float tk = temp[kidx];

    float w8[8];
#pragma unroll
    for (int j = 0; j < 8; ++j) w8[j] = fabsf(wfn[(fl << 3) + j]);

    // prologue: first node
    int node = wv;
    int rs0 = rowstart[node], rs1 = rowstart[node + 1];
    float d = dis[node];
    uint2 sv = *(const uint2*)(g + ((long)node << 4) + (fl << 3));
    int c0 = csr[min(rs0 + slot, etot - 1)];

    for (;;) {
        const int nnext = node + NW;
        const bool has_next = nnext < n;

        // (1) next node's independent loads
        int rs0n, rs1n; float dn; uint2 svn;
        if (has_next) {
            rs0n = rowstart[nnext];
            rs1n = rowstart[nnext + 1];
            dn = dis[nnext];
            svn = *(const uint2*)(g + ((long)nnext << 4) + (fl << 3));
        }

        // (2) gather: 32 edges/round, 8B fp8 per lane
        float a[8];
#pragma unroll
        for (int j = 0; j < 8; ++j) a[j] = 0.0f;
        if (rs0 + slot < rs1) {
            uint2 v = *(const uint2*)(g + ((long)c0 << 4) + (fl << 3));
            fp8x8_acc(v, a);
        }
        for (int e2 = rs0 + slot + 32; e2 < rs1; e2 += 32) {
            int s1 = csr[e2];
            uint2 v = *(const uint2*)(g + ((long)s1 << 4) + (fl << 3));
            fp8x8_acc(v, a);
        }

        // (3) butterfly over 32 slots, packed f16x2
        {
            unsigned int pk[4];
#pragma unroll
            for (int i = 0; i < 4; ++i) {
                __half2 hh = __floats2half2_rn(a[2 * i], a[2 * i + 1]);
                pk[i] = *(unsigned int*)&hh;
            }
#pragma unroll
            for (int off = 2; off < 64; off <<= 1) {
#pragma unroll
                for (int i = 0; i < 4; ++i) {
                    unsigned int o = (unsigned int)__shfl_xor((int)pk[i], off);
                    __half2 s = *(__half2*)&pk[i] + *(__half2*)&o;
                    pk[i] = *(unsigned int*)&s;
                }
            }
#pragma unroll
            for (int i = 0; i < 4; ++i) {
                float2 f = __half22float2(*(__half2*)&pk[i]);
                a[2 * i] = f.x;
                a[2 * i + 1] = f.y;
            }
        }

        // (4) self-loop + dis scale + riemann
        {
            float s8[8];
#pragma unroll
            for (int j = 0; j < 8; ++j) s8[j] = 0.0f;
            fp8x8_acc(sv, s8);
#pragma unroll
            for (int j = 0; j < 8; ++j) a[j] = (a[j] + s8[j]) * d;
        }
        float p = 0.0f;
#pragma unroll
        for (int j = 0; j < 8; ++j) p += a[j] * a[j] * w8[j];
        p += __shfl_xor(p, 1);
        float inv = 1.0f / (sqrtf(p + 0.01f) + 0.01f);

        // (5) writes (2 lanes per node: slot 0, fl 0/1)
        if (slot == 0) {
            long base = ((long)node << 4) + (fl << 3);
            float4 h0 = *(const float4*)(hidden + base);
            float4 h1 = *(const float4*)(hidden + base + 4);
            h0.x = fmaf(tk, a[0] * inv, h0.x);
            h0.y = fmaf(tk, a[1] * inv, h0.y);
            h0.z = fmaf(tk, a[2] * inv, h0.z);
            h0.w = fmaf(tk, a[3] * inv, h0.w);
            h1.x = fmaf(tk, a[4] * inv, h1.x);
            h1.y = fmaf(tk, a[5] * inv, h1.y);
            h1.z = fmaf(tk, a[6] * inv, h1.z);
            h1.w = fmaf(tk, a[7] * inv, h1.w);
            *(float4*)(hidden + base) = h0;
            *(float4*)(hidden + base + 4) = h1;
            if (writeg) {
                float di = d * inv;
                uint2 o;
                o.x = fp8pk4(di * a[0], di * a[1], di * a[2], di * a[3]);
                o.y = fp8pk4(di * a[4], di * a[5], di * a[6], di * a[7]);
                *(uint2*)(gn + base) = o;
            }
        }

        if (!has_next) break;

        // (6) prefetch next node's first-round csr
        int c0n = csr[min(rs0n + slot, etot - 1)];

        // (7) rotate
        node = nnext;
        rs0 = rs0n; rs1 = rs1n; d = dn; sv = svn; c0 = c0n;
    }
}

// ---------------- launch ----------------

static inline long align4up(long w) { return (w + 3) & ~3L; }

extern "C" void kernel_launch(void* const* d_in, const int* in_sizes, int n_in,
                              void* d_out, int out_size, void* d_ws, size_t ws_size,
                              hipStream_t stream) {
    const float* x          = (const float*)d_in[0];
    const int*   edge_index = (const int*)d_in[1];
    const float* W1         = (const float*)d_in[2];
    const float* b1         = (const float*)d_in[3];
    const float* W2         = (const float*)d_in[4];
    const float* b2         = (const float*)d_in[5];
    const float* temp       = (const float*)d_in[6];
    const float* w_for_norm = (const float*)d_in[7];
    float* hidden = (float*)d_out;

    const int n = in_sizes[0] / F_IN;
    const int e = in_sizes[1] / 2;
    const int* rows = edge_index;        // sources
    const int* cols = edge_index + e;    // destinations
    const int nb = (n + BKT_NODES - 1) / BKT_NODES;

    long off = 0;
    int* wsI = (int*)d_ws;
    int* bcnt      = wsI + off; off = align4up(off + NBKT_MAX);
    int* bstart    = wsI + off; off = align4up(off + NBKT_MAX + 1);
    int* bcur      = wsI + off; off = align4up(off + NBKT_MAX);
    int* rowstart  = wsI + off; off = align4up(off + n + 1);
    float* dis     = (float*)(wsI + off); off = align4up(off + n);
    uint32* stage  = (uint32*)(wsI + off); off = align4up(off + e);
    int* csr       = wsI + off; off = align4up(off + e);
    unsigned short* w1t = (unsigned short*)(wsI + off); off = align4up(off + HD * F_IN / 2);
    unsigned short* w2t = (unsigned short*)(wsI + off); off = align4up(off + CD * HD / 2);
    unsigned char* gA = (unsigned char*)(wsI + off); off = align4up(off + n * 4);
    unsigned char* gB = (unsigned char*)(wsI + off); off = align4up(off + n * 4);

    const int B = 256;
    const int nbC = (e + EPB - 1) / EPB;

    zero_kernel<<<(nb + B - 1) / B, B, 0, stream>>>(bcnt, nb);
    bucket_hist_kernel<<<nbC, B, 0, stream>>>(cols, bcnt, e, nb);
    bucket_scan_kernel<<<1, B, 0, stream>>>(bcnt, bstart, bcur, nb);
    scatter_bin_kernel<<<nbC, B, 0, stream>>>(rows, cols, bcur, stage, e, nb);
    bucket_sort_kernel<<<nb, B, 0, stream>>>(stage, bstart, rowstart, dis, csr, n, e);
    convw_kernel<<<(HD * F_IN + CD * HD + B - 1) / B, B, 0, stream>>>(W1, W2, w1t, w2t);

    mlp_kernel<<<(n + 63) / 64, B, 0, stream>>>(x, w1t, b1, w2t, b2, dis, temp,
                                                w_for_norm, gA, hidden, n);

    unsigned char* gsrc = gA;
    unsigned char* gdst = gB;
    for (int k = 1; k <= K_HOPS; ++k) {
        hop_kernel<<<HOP_BLOCKS, B, 0, stream>>>(
            gsrc, gdst, hidden, dis, rowstart, csr, temp, w_for_norm,
            k, (k < K_HOPS) ? 1 : 0, n, e);
        unsigned char* tmp = gsrc; gsrc = gdst; gdst = tmp;
    }
}